// Round 1
// baseline (389.920 us; speedup 1.0000x reference)
//
#include <hip/hip_runtime.h>

typedef _Float16 f16;
typedef f16 h2 __attribute__((ext_vector_type(2)));
typedef f16 h8 __attribute__((ext_vector_type(8)));
typedef unsigned int uint;

#define WG_SIZE 256
#define BM 32
#define NPOS 900
#define NCHUNK 57   // ceil(900/16)

// LDS activation strides (in halves)
#define SA 136
#define SZ 72
#define SGF 24
// transposed-weight strides (in halves) = Kin + 8
#define SW128 136
#define SW64 72
#define SW208 216

// ws layout (halves)
#define N_W1H (9000*128)
#define OFF_W2 0
#define OFF_WY 17408
#define OFF_WZ 34816
#define OFF_RZ1 43520
#define OFF_RZ2 57344
#define OFF_RY1 61952
#define OFF_RY2 75776
#define OFF_SEL1 84992
#define OFF_SEL2 93696
#define N_SMH 98304

__device__ __forceinline__ float geluf(float x){
  return 0.5f * x * (1.0f + erff(x * 0.70710678118654752f));
}

#if defined(__has_builtin)
#if __has_builtin(__builtin_amdgcn_fdot2)
#define HAVE_FDOT2 1
#endif
#endif

__device__ __forceinline__ float fdot2f(h2 a, h2 b, float c){
#ifdef HAVE_FDOT2
  return __builtin_amdgcn_fdot2(a, b, c, false);
#else
  return c + (float)a[0]*(float)b[0] + (float)a[1]*(float)b[1];
#endif
}

union H8u { h8 v; h2 p[4]; };

// matvec partial: x-row (f16 LDS) against transposed weights WT[o][k], 8 threads/sample,
// thread u owns outputs o = u + 8*j.
template<int KLEN, int NO8>
__device__ __forceinline__ void mv_part(const f16* __restrict__ xrow,
                                        const f16* __restrict__ WT,
                                        int sw, int koff, float* acc, int u){
  #pragma unroll 4
  for (int kk = 0; kk < KLEN; kk += 8){
    H8u x; x.v = *(const h8*)(xrow + kk);
    #pragma unroll
    for (int j = 0; j < NO8; ++j){
      H8u w; w.v = *(const h8*)(WT + (u + 8*j)*sw + koff + kk);
      acc[j] = fdot2f(x.p[0], w.p[0], acc[j]);
      acc[j] = fdot2f(x.p[1], w.p[1], acc[j]);
      acc[j] = fdot2f(x.p[2], w.p[2], acc[j]);
      acc[j] = fdot2f(x.p[3], w.p[3], acc[j]);
    }
  }
}

template<int BYTES>
__device__ __forceinline__ void stageW(const f16* __restrict__ gsrc, char* ldst, int t){
  const char* g = (const char*)gsrc;
  #pragma unroll
  for (int off = 0; off < BYTES; off += 4096){
    int o = off + t*16;
    if (o < BYTES) *(uint4*)(ldst + o) = *(const uint4*)(g + o);
  }
}

// ---------------- prep: f32 -> f16 (+ transpose/pad small weights) ----------------
__global__ void prep_kernel(const float* __restrict__ w1,
  const float* __restrict__ w2, const float* __restrict__ wy, const float* __restrict__ wz,
  const float* __restrict__ rz1, const float* __restrict__ rz2,
  const float* __restrict__ ry1, const float* __restrict__ ry2,
  const float* __restrict__ sel1, const float* __restrict__ sel2, f16* __restrict__ ws)
{
  int idx = blockIdx.x * WG_SIZE + threadIdx.x;
  if (idx < N_W1H){ ws[idx] = (f16)w1[idx]; return; }
  int r = idx - N_W1H;
  if (r >= N_SMH) return;
  f16* dst = ws + N_W1H;
  const float* src; int kin, nout, str, off;
  if (r < OFF_WY)       { src=w2;   kin=128; nout=128; str=SW128; off=OFF_W2; }
  else if (r < OFF_WZ)  { src=wy;   kin=128; nout=128; str=SW128; off=OFF_WY; }
  else if (r < OFF_RZ1) { src=wz;   kin=128; nout=64;  str=SW128; off=OFF_WZ; }
  else if (r < OFF_RZ2) { src=rz1;  kin=208; nout=64;  str=SW208; off=OFF_RZ1; }
  else if (r < OFF_RY1) { src=rz2;  kin=64;  nout=64;  str=SW64;  off=OFF_RZ2; }
  else if (r < OFF_RY2) { src=ry1;  kin=208; nout=64;  str=SW208; off=OFF_RY1; }
  else if (r < OFF_SEL1){ src=ry2;  kin=64;  nout=128; str=SW64;  off=OFF_RY2; }
  else if (r < OFF_SEL2){ src=sel1; kin=128; nout=64;  str=SW128; off=OFF_SEL1; }
  else                  { src=sel2; kin=64;  nout=64;  str=SW64;  off=OFF_SEL2; }
  int l = r - off;
  int o = l / str;
  int k = l - o*str;
  dst[r] = (k < kin) ? (f16)src[k*nout + o] : (f16)0.0f;
}

// ---------------- fused main kernel ----------------
__global__ __launch_bounds__(WG_SIZE, 1) void fused_kernel(
  const int* __restrict__ grd, const float* __restrict__ gfeat, const float* __restrict__ gum,
  const float* __restrict__ b1, const float* __restrict__ b2,
  const float* __restrict__ by, const float* __restrict__ bz,
  const float* __restrict__ rzb1, const float* __restrict__ rzb2,
  const float* __restrict__ ryb1, const float* __restrict__ ryb2,
  const float* __restrict__ sb1, const float* __restrict__ sb2,
  const f16* __restrict__ ws, float* __restrict__ out)
{
  __shared__ __align__(16) char Ubuf[52224];       // phase E slices+gidx / later staged weights + logits
  __shared__ __align__(16) char Abuf[BM*SA*2];     // h, then y
  __shared__ __align__(16) char Bbuf[BM*SA*2];     // h2, then hid
  __shared__ __align__(16) char Zbuf[BM*SZ*2];     // z
  __shared__ __align__(16) char Gbuf[BM*SGF*2];    // grid_features (f16)

  const int t = threadIdx.x;
  const int s0 = blockIdx.x * BM;

  f16* wsl = (f16*)Ubuf;           // [160][128] f16 slice chunk
  char* gix = Ubuf + 40960;        // [32][20] u8 colors

  // ================= phase E: h = gelu(onehot(grid) @ w1 + b1) =================
  {
    const int lane5 = t & 31;
    const int fl = lane5 * 4;      // features fl..fl+3
    const int sl = t >> 5;         // sample sub-lane 0..7

    h2 accA[4], accB[4];
    float4 accF[4];
    #pragma unroll
    for (int i=0;i<4;i++){
      accA[i][0]=(f16)0.f; accA[i][1]=(f16)0.f;
      accB[i][0]=(f16)0.f; accB[i][1]=(f16)0.f;
      accF[i].x=0.f; accF[i].y=0.f; accF[i].z=0.f; accF[i].w=0.f;
    }

    uint4 wreg[10];
    uint4 greg; greg.x=0; greg.y=0; greg.z=0; greg.w=0;

    auto loadChunk = [&](int c){
      const int p0c = c*16;
      int pc = NPOS - p0c; if (pc > 16) pc = 16;
      const int bytes = pc * 2560;
      const char* src = (const char*)ws + p0c * 2560;
      #pragma unroll
      for (int i2=0;i2<10;i2++){
        int o = i2*4096 + t*16;
        if (o < bytes) wreg[i2] = *(const uint4*)(src + o);
      }
      if (t < 128){
        int sS = t>>2, q = t&3;
        if (q*4 < pc) greg = *(const uint4*)((const uint*)grd + (s0+sS)*NPOS + p0c + q*4);
      }
    };
    auto writeChunk = [&](int c){
      const int p0c = c*16;
      int pc = NPOS - p0c; if (pc>16) pc=16;
      const int bytes = pc*2560;
      #pragma unroll
      for (int i2=0;i2<10;i2++){
        int o = i2*4096 + t*16;
        if (o < bytes) *(uint4*)(Ubuf + o) = wreg[i2];
      }
      if (t < 128){
        int sS=t>>2, q=t&3;
        if (q*4 < pc){
          uint pk = (greg.x & 255u) | ((greg.y & 255u)<<8) | ((greg.z & 255u)<<16) | ((greg.w & 255u)<<24);
          *(uint*)(gix + sS*20 + q*4) = pk;
        }
      }
    };

    loadChunk(0);
    writeChunk(0);
    loadChunk(1);
    __syncthreads();

    for (int c=0;c<NCHUNK;c++){
      int pc = NPOS - c*16; if (pc>16) pc=16;
      #pragma unroll
      for (int i=0;i<4;i++){
        const int sS = sl + 8*i;
        const char* gr = gix + sS*20;
        uint g4[4];
        #pragma unroll
        for (int q=0;q<4;q++) g4[q] = *(const uint*)(gr + q*4);
        #pragma unroll
        for (int pp=0;pp<16;pp++){
          if (pp < pc){
            int g = (g4[pp>>2] >> ((pp&3)*8)) & 255;
            int row = pp*10 + g;
            union { uint2 u; h2 h[2]; } w;
            w.u = *(const uint2*)(wsl + row*128 + fl);
            accA[i] += w.h[0];
            accB[i] += w.h[1];
          }
        }
      }
      // merge 16-term f16 partials into f32
      #pragma unroll
      for (int i=0;i<4;i++){
        accF[i].x += (float)accA[i][0];
        accF[i].y += (float)accA[i][1];
        accF[i].z += (float)accB[i][0];
        accF[i].w += (float)accB[i][1];
        accA[i][0]=(f16)0.f; accA[i][1]=(f16)0.f;
        accB[i][0]=(f16)0.f; accB[i][1]=(f16)0.f;
      }
      __syncthreads();
      if (c+1 < NCHUNK){
        writeChunk(c+1);
        if (c+2 < NCHUNK) loadChunk(c+2);
        __syncthreads();
      }
    }

    // bias + gelu -> A (f16)
    float4 bb = *(const float4*)(b1 + fl);
    f16* A = (f16*)Abuf;
    #pragma unroll
    for (int i=0;i<4;i++){
      int sS = sl + 8*i;
      float x0 = geluf(accF[i].x + bb.x);
      float x1 = geluf(accF[i].y + bb.y);
      float x2 = geluf(accF[i].z + bb.z);
      float x3 = geluf(accF[i].w + bb.w);
      h2 lo; lo[0]=(f16)x0; lo[1]=(f16)x1;
      h2 hi; hi[0]=(f16)x2; hi[1]=(f16)x3;
      *(h2*)(A + sS*SA + fl) = lo;
      *(h2*)(A + sS*SA + fl + 2) = hi;
    }
  }

  // ================= phases 2-4 =================
  const f16* SMW = ws + N_W1H;
  f16* WB = (f16*)Ubuf;
  f16* A  = (f16*)Abuf;
  f16* Bb = (f16*)Bbuf;
  f16* Zb = (f16*)Zbuf;
  f16* Gb = (f16*)Gbuf;
  float* Lb = (float*)(Ubuf + 28672);

  const int sS = t >> 3;
  const int u  = t & 7;
  const int gsamp = s0 + sS;

  // stage w2^T, and grid_features
  stageW<34816>(SMW + OFF_W2, Ubuf, t);
  if (t < 128){
    int ss = t>>2, q = t&3;
    float4 g4 = *(const float4*)(gfeat + (s0+ss)*16 + q*4);
    h2 a; a[0]=(f16)g4.x; a[1]=(f16)g4.y;
    h2 b; b[0]=(f16)g4.z; b[1]=(f16)g4.w;
    *(h2*)(Gb + ss*SGF + q*4)     = a;
    *(h2*)(Gb + ss*SGF + q*4 + 2) = b;
  }
  __syncthreads();

  // enc L2: h2 = gelu(h @ w2 + b2)
  {
    float acc[16];
    #pragma unroll
    for (int j=0;j<16;j++) acc[j] = b2[u + 8*j];
    mv_part<128,16>(A + sS*SA, WB, SW128, 0, acc, u);
    #pragma unroll
    for (int j=0;j<16;j++) Bb[sS*SA + u + 8*j] = (f16)geluf(acc[j]);
  }
  __syncthreads();

  // heads: y = h2@wy+by ; z = h2@wz+bz
  stageW<52224>(SMW + OFF_WY, Ubuf, t);
  __syncthreads();
  {
    float acc[16];
    #pragma unroll
    for (int j=0;j<16;j++) acc[j] = by[u+8*j];
    mv_part<128,16>(Bb + sS*SA, WB, SW128, 0, acc, u);
    #pragma unroll
    for (int j=0;j<16;j++) A[sS*SA + u+8*j] = (f16)acc[j];
    float accz[8];
    #pragma unroll
    for (int j=0;j<8;j++) accz[j] = bz[u+8*j];
    mv_part<128,8>(Bb + sS*SA, WB + 17408, SW128, 0, accz, u);
    #pragma unroll
    for (int j=0;j<8;j++) Zb[sS*SZ + u+8*j] = (f16)accz[j];
  }
  __syncthreads();

  // 3 refinement cycles
  #pragma unroll 1
  for (int cyc=0; cyc<3; ++cyc){
    stageW<36864>(SMW + OFF_RZ1, Ubuf, t);   // rz1^T + rz2^T
    __syncthreads();
    { // hid = gelu([y,z,gf] @ rz1 + rzb1)
      float acc[8];
      #pragma unroll
      for (int j=0;j<8;j++) acc[j] = rzb1[u+8*j];
      mv_part<128,8>(A  + sS*SA,  WB, SW208, 0,   acc, u);
      mv_part<64,8>(Zb + sS*SZ,  WB, SW208, 128, acc, u);
      mv_part<16,8>(Gb + sS*SGF, WB, SW208, 192, acc, u);
      #pragma unroll
      for (int j=0;j<8;j++) Bb[sS*SA + u+8*j] = (f16)geluf(acc[j]);
    }
    __syncthreads();
    { // z = hid @ rz2 + rzb2
      float acc[8];
      #pragma unroll
      for (int j=0;j<8;j++) acc[j] = rzb2[u+8*j];
      mv_part<64,8>(Bb + sS*SA, WB + 13824, SW64, 0, acc, u);
      #pragma unroll
      for (int j=0;j<8;j++) Zb[sS*SZ + u+8*j] = (f16)acc[j];
    }
    __syncthreads();
    stageW<46080>(SMW + OFF_RY1, Ubuf, t);   // ry1^T + ry2^T
    __syncthreads();
    { // hid = gelu([z,y,gf] @ ry1 + ryb1)
      float acc[8];
      #pragma unroll
      for (int j=0;j<8;j++) acc[j] = ryb1[u+8*j];
      mv_part<64,8>(Zb + sS*SZ,  WB, SW208, 0,   acc, u);
      mv_part<128,8>(A  + sS*SA,  WB, SW208, 64,  acc, u);
      mv_part<16,8>(Gb + sS*SGF, WB, SW208, 192, acc, u);
      #pragma unroll
      for (int j=0;j<8;j++) Bb[sS*SA + u+8*j] = (f16)geluf(acc[j]);
    }
    __syncthreads();
    { // y = hid @ ry2 + ryb2
      float acc[16];
      #pragma unroll
      for (int j=0;j<16;j++) acc[j] = ryb2[u+8*j];
      mv_part<64,16>(Bb + sS*SA, WB + 13824, SW64, 0, acc, u);
      #pragma unroll
      for (int j=0;j<16;j++) A[sS*SA + u+8*j] = (f16)acc[j];
    }
    __syncthreads();
  }

  // selector
  stageW<26624>(SMW + OFF_SEL1, Ubuf, t);    // sel1^T + sel2^T
  __syncthreads();
  {
    float acc[8];
    #pragma unroll
    for (int j=0;j<8;j++) acc[j] = sb1[u+8*j];
    mv_part<128,8>(A + sS*SA, WB, SW128, 0, acc, u);
    #pragma unroll
    for (int j=0;j<8;j++) Bb[sS*SA + u+8*j] = (f16)geluf(acc[j]);
  }
  __syncthreads();
  {
    float acc[8];
    #pragma unroll
    for (int j=0;j<8;j++) acc[j] = sb2[u+8*j];
    mv_part<64,8>(Bb + sS*SA, WB + 8704, SW64, 0, acc, u);
    #pragma unroll
    for (int j=0;j<8;j++){
      acc[j] += gum[gsamp*64 + u + 8*j];
      Lb[sS*68 + u + 8*j] = acc[j];
    }
  }
  __syncthreads();
  // softmax (each of the 8 threads of a sample redundantly reduces its row)
  {
    const float* row = Lb + sS*68;
    float m = -3.0e38f;
    #pragma unroll
    for (int k4=0;k4<16;k4++){
      float4 v = *(const float4*)(row + k4*4);
      m = fmaxf(m, fmaxf(fmaxf(v.x,v.y), fmaxf(v.z,v.w)));
    }
    float ssum = 0.f;
    #pragma unroll
    for (int k4=0;k4<16;k4++){
      float4 v = *(const float4*)(row + k4*4);
      ssum += __expf(v.x-m)+__expf(v.y-m)+__expf(v.z-m)+__expf(v.w-m);
    }
    float inv = 1.0f / ssum;
    #pragma unroll
    for (int j=0;j<8;j++){
      int o = u + 8*j;
      out[gsamp*64 + o] = __expf(row[o]-m) * inv;
    }
  }
}

extern "C" void kernel_launch(void* const* d_in, const int* in_sizes, int n_in,
                              void* d_out, int out_size, void* d_ws, size_t ws_size,
                              hipStream_t stream) {
  const int*   grd   = (const int*)d_in[0];
  const float* gfeat = (const float*)d_in[1];
  const float* gum   = (const float*)d_in[2];
  const float* w1    = (const float*)d_in[3];
  const float* b1    = (const float*)d_in[4];
  const float* w2    = (const float*)d_in[5];
  const float* b2    = (const float*)d_in[6];
  const float* wy    = (const float*)d_in[7];
  const float* byb   = (const float*)d_in[8];
  const float* wz    = (const float*)d_in[9];
  const float* bz    = (const float*)d_in[10];
  const float* rz1   = (const float*)d_in[11];
  const float* rzb1  = (const float*)d_in[12];
  const float* rz2   = (const float*)d_in[13];
  const float* rzb2  = (const float*)d_in[14];
  const float* ry1   = (const float*)d_in[15];
  const float* ryb1  = (const float*)d_in[16];
  const float* ry2   = (const float*)d_in[17];
  const float* ryb2  = (const float*)d_in[18];
  const float* sel1  = (const float*)d_in[19];
  const float* sb1   = (const float*)d_in[20];
  const float* sel2  = (const float*)d_in[21];
  const float* sb2   = (const float*)d_in[22];

  f16* ws = (f16*)d_ws;
  float* outp = (float*)d_out;

  const int prep_total = N_W1H + N_SMH;
  prep_kernel<<<(prep_total + WG_SIZE - 1)/WG_SIZE, WG_SIZE, 0, stream>>>(
      w1, w2, wy, wz, rz1, rz2, ry1, ry2, sel1, sel2, ws);

  fused_kernel<<<8192/BM, WG_SIZE, 0, stream>>>(
      grd, gfeat, gum, b1, b2, byb, bz, rzb1, rzb2, ryb1, ryb2, sb1, sb2, ws, outp);
}

// Round 2
// 163.353 us; speedup vs baseline: 2.3870x; 2.3870x over previous
//
#include <hip/hip_runtime.h>

typedef _Float16 f16;
typedef f16 h2 __attribute__((ext_vector_type(2)));
typedef f16 h8 __attribute__((ext_vector_type(8)));
typedef unsigned int uint;

#define WG_SIZE 256
#define BM 16
#define NCH 113          // ceil(900/8)

// LDS strides (halves / floats)
#define SA 136
#define SZ 72
#define SGF 24
#define SLOG 68
#define CSTR 904         // color row stride (bytes)

// ws layout (halves)
#define N_W1H 1152000    // 9000*128
#define OW2 0
#define OWY 16384
#define OWZ 32768
#define ORZ1 40960
#define ORZ2 54272
#define ORY1 58368
#define ORY2 71680
#define OS1 79872
#define OS2 88064
#define N_SMH 92160

__device__ __forceinline__ float geluf(float x){
  return 0.5f * x * (1.0f + erff(x * 0.70710678118654752f));
}
__device__ __forceinline__ float fdot2f(h2 a, h2 b, float c){
  return __builtin_amdgcn_fdot2(a, b, c, false);
}
union H8u { h8 v; h2 p[4]; };

__device__ __forceinline__ void gll16(const void* g, void* l){
  __builtin_amdgcn_global_load_lds((const __attribute__((address_space(1))) void*)g,
                                   (__attribute__((address_space(3))) void*)l, 16, 0, 0);
}
__device__ __forceinline__ void wave_sync(){
  asm volatile("s_waitcnt lgkmcnt(0)" ::: "memory");
}

// matvec vs prep-packed global weights: layout [j][kk][u][8 halves]
// thread u owns outputs o = u + 16*j; W element (o, k=kk*8+f) at ((j*KT8+kk)*16+u)*8 + f
template<int NO, int KC, int KT8>
__device__ __forceinline__ void mvg(const f16* __restrict__ xrow, const f16* __restrict__ Wg,
                                    int kk0, float* acc, int u){
  #pragma unroll 2
  for (int kk = 0; kk < KC; ++kk){
    H8u x; x.v = *(const h8*)(xrow + kk*8);
    #pragma unroll
    for (int j = 0; j < NO; ++j){
      H8u w; w.v = *(const h8*)(Wg + (size_t)(((j*KT8 + kk0 + kk) << 4) + u) * 8);
      acc[j] = fdot2f(x.p[0], w.p[0], acc[j]);
      acc[j] = fdot2f(x.p[1], w.p[1], acc[j]);
      acc[j] = fdot2f(x.p[2], w.p[2], acc[j]);
      acc[j] = fdot2f(x.p[3], w.p[3], acc[j]);
    }
  }
}

template<int PC>
__device__ __forceinline__ void chunkAcc(const f16* __restrict__ wb, uint2 cc, int foff, float* accF){
  h2 a0, a1, a2, a3;
  a0[0]=(f16)0; a0[1]=(f16)0; a1=a0; a2=a0; a3=a0;
  #pragma unroll
  for (int p = 0; p < PC; ++p){
    uint g = ((p < 4) ? (cc.x >> (8*p)) : (cc.y >> (8*(p-4)))) & 255u;
    H8u w; w.v = *(const h8*)(wb + (uint)(p*10)*128u + g*128u + (uint)foff);
    a0 += w.p[0]; a1 += w.p[1]; a2 += w.p[2]; a3 += w.p[3];
  }
  accF[0]+=(float)a0[0]; accF[1]+=(float)a0[1];
  accF[2]+=(float)a1[0]; accF[3]+=(float)a1[1];
  accF[4]+=(float)a2[0]; accF[5]+=(float)a2[1];
  accF[6]+=(float)a3[0]; accF[7]+=(float)a3[1];
}

// ---------------- prep: w1 -> f16 copy; small weights -> packed fragment order ----------------
__global__ void prep_kernel(const float* __restrict__ w1,
  const float* __restrict__ w2, const float* __restrict__ wy, const float* __restrict__ wz,
  const float* __restrict__ rz1, const float* __restrict__ rz2,
  const float* __restrict__ ry1, const float* __restrict__ ry2,
  const float* __restrict__ sel1, const float* __restrict__ sel2, f16* __restrict__ ws)
{
  int idx = blockIdx.x * WG_SIZE + threadIdx.x;
  if (idx < N_W1H){ ws[idx] = (f16)w1[idx]; return; }
  int r = idx - N_W1H;
  if (r >= N_SMH) return;
  const float* src; int N, K, off;
  if      (r < OWY) { src=w2;   N=128; K=128; off=OW2; }
  else if (r < OWZ) { src=wy;   N=128; K=128; off=OWY; }
  else if (r < ORZ1){ src=wz;   N=64;  K=128; off=OWZ; }
  else if (r < ORZ2){ src=rz1;  N=64;  K=208; off=ORZ1; }
  else if (r < ORY1){ src=rz2;  N=64;  K=64;  off=ORZ2; }
  else if (r < ORY2){ src=ry1;  N=64;  K=208; off=ORY1; }
  else if (r < OS1) { src=ry2;  N=128; K=64;  off=ORY2; }
  else if (r < OS2) { src=sel1; N=64;  K=128; off=OS1; }
  else              { src=sel2; N=64;  K=64;  off=OS2; }
  int l = r - off;
  int f = l & 7;
  int u = (l >> 3) & 15;
  int q = l >> 7;
  int K8 = K >> 3;
  int kk = q % K8;
  int j  = q / K8;
  ws[N_W1H + r] = (f16)src[(kk*8 + f)*N + (u + 16*j)];
}

// ---------------- fused main kernel ----------------
extern "C" __global__ __launch_bounds__(WG_SIZE, 2) void fused_kernel(
  const int* __restrict__ grd, const float* __restrict__ gfeat, const float* __restrict__ gum,
  const float* __restrict__ b1, const float* __restrict__ b2,
  const float* __restrict__ by, const float* __restrict__ bz,
  const float* __restrict__ rzb1, const float* __restrict__ rzb2,
  const float* __restrict__ ryb1, const float* __restrict__ ryb2,
  const float* __restrict__ sb1, const float* __restrict__ sb2,
  const f16* __restrict__ ws, float* __restrict__ out)
{
  __shared__ __align__(16) char Wbuf[2][20480];
  __shared__ __align__(16) char colL[16*CSTR];
  __shared__ __align__(16) f16 A [16*SA];
  __shared__ __align__(16) f16 Bb[16*SA];
  __shared__ __align__(16) f16 Zb[16*SZ];
  __shared__ __align__(16) f16 Gb[16*SGF];
  __shared__ __align__(16) float Lb[16*SLOG];

  const int t  = threadIdx.x;
  const int s0 = blockIdx.x * BM;
  const int flane = t & 15;
  const int slane = t >> 4;
  const int foff  = flane * 8;

  // ---- prologue: pack colors (u8) + stage grid features ----
  {
    const uint4* gv = (const uint4*)(grd + (size_t)s0 * 900);
    #pragma unroll
    for (int it = 0; it < 15; ++it){
      int idx4 = it*256 + t;
      if (idx4 < 3600){
        uint4 v = gv[idx4];
        uint pk = (v.x & 255u) | ((v.y & 255u) << 8) | ((v.z & 255u) << 16) | ((v.w & 255u) << 24);
        uint s  = (uint)(idx4 * 9321u) >> 21;   // idx4 / 225
        uint p4 = (uint)idx4 - s * 225u;
        *(uint*)(colL + s*CSTR + p4*4) = pk;
      }
    }
    Gb[slane*SGF + flane] = (f16)gfeat[(size_t)(s0 + slane)*16 + flane];
  }
  __syncthreads();   // drains all prior vmem -> vmcnt baseline 0

  // ---- phase E: h = gelu(onehot(grid) @ w1 + b1), gather form ----
  float accF[8] = {0,0,0,0,0,0,0,0};

  auto issueChunk = [&](int c, char* dst){
    const char* src = (const char*)(ws + (size_t)c * 10240);
    #pragma unroll
    for (int i = 0; i < 5; ++i)
      gll16(src + i*4096 + t*16, dst + i*4096 + t*16);
  };

  issueChunk(0, Wbuf[0]);
  issueChunk(1, Wbuf[1]);
  asm volatile("s_waitcnt vmcnt(5)" ::: "memory");
  __builtin_amdgcn_s_barrier();

  uint2 cc = *(const uint2*)(colL + slane*CSTR);
  #pragma unroll 1
  for (int c = 0; c < NCH; ++c){
    f16* wb = (f16*)Wbuf[c & 1];
    uint2 ccn = cc;
    if (c + 1 < NCH) ccn = *(const uint2*)(colL + slane*CSTR + (c+1)*8);
    if (c != NCH-1) chunkAcc<8>(wb, cc, foff, accF);
    else            chunkAcc<4>(wb, cc, foff, accF);
    cc = ccn;
    __builtin_amdgcn_s_barrier();
    if (c + 2 < NCH){
      issueChunk(c + 2, (char*)wb);
      asm volatile("s_waitcnt vmcnt(5)" ::: "memory");
    } else if (c + 2 == NCH){
      asm volatile("s_waitcnt vmcnt(0)" ::: "memory");
    }
    __builtin_amdgcn_s_barrier();
  }

  { // bias + gelu -> h (f16, one b128 store)
    float4 bl = *(const float4*)(b1 + foff);
    float4 bh = *(const float4*)(b1 + foff + 4);
    h8 hv;
    hv[0] = (f16)geluf(accF[0] + bl.x);
    hv[1] = (f16)geluf(accF[1] + bl.y);
    hv[2] = (f16)geluf(accF[2] + bl.z);
    hv[3] = (f16)geluf(accF[3] + bl.w);
    hv[4] = (f16)geluf(accF[4] + bh.x);
    hv[5] = (f16)geluf(accF[5] + bh.y);
    hv[6] = (f16)geluf(accF[6] + bh.z);
    hv[7] = (f16)geluf(accF[7] + bh.w);
    *(h8*)(A + slane*SA + foff) = hv;
  }
  wave_sync();

  // ---- phases 2-4: wave-independent, weights direct from global (L2-hot) ----
  const f16* SMW = ws + N_W1H;
  const int u  = flane;
  const int sS = slane;
  const size_t gsamp = (size_t)(s0 + sS);
  const f16* xA = A  + sS*SA;
  const f16* xB = Bb + sS*SA;
  const f16* xZ = Zb + sS*SZ;
  const f16* xG = Gb + sS*SGF;

  // enc L2: h2 = gelu(h @ w2 + b2)
  {
    float acc[8];
    #pragma unroll
    for (int j=0;j<8;j++) acc[j] = b2[u + 16*j];
    mvg<8,16,16>(xA, SMW + OW2, 0, acc, u);
    #pragma unroll
    for (int j=0;j<8;j++) Bb[sS*SA + u + 16*j] = (f16)geluf(acc[j]);
  }
  wave_sync();

  // heads: y = h2@wy+by ; z = h2@wz+bz
  {
    float acc[8];
    #pragma unroll
    for (int j=0;j<8;j++) acc[j] = by[u + 16*j];
    mvg<8,16,16>(xB, SMW + OWY, 0, acc, u);
    float az[4];
    #pragma unroll
    for (int j=0;j<4;j++) az[j] = bz[u + 16*j];
    mvg<4,16,16>(xB, SMW + OWZ, 0, az, u);
    #pragma unroll
    for (int j=0;j<8;j++) A[sS*SA + u + 16*j] = (f16)acc[j];
    #pragma unroll
    for (int j=0;j<4;j++) Zb[sS*SZ + u + 16*j] = (f16)az[j];
  }
  wave_sync();

  // 3 refinement cycles
  #pragma unroll 1
  for (int cyc = 0; cyc < 3; ++cyc){
    { // hid = gelu([y,z,gf] @ rz1 + rzb1)
      float acc[4];
      #pragma unroll
      for (int j=0;j<4;j++) acc[j] = rzb1[u + 16*j];
      mvg<4,16,26>(xA, SMW + ORZ1, 0,  acc, u);
      mvg<4, 8,26>(xZ, SMW + ORZ1, 16, acc, u);
      mvg<4, 2,26>(xG, SMW + ORZ1, 24, acc, u);
      #pragma unroll
      for (int j=0;j<4;j++) Bb[sS*SA + u + 16*j] = (f16)geluf(acc[j]);
    }
    wave_sync();
    { // z = hid @ rz2 + rzb2
      float acc[4];
      #pragma unroll
      for (int j=0;j<4;j++) acc[j] = rzb2[u + 16*j];
      mvg<4,8,8>(xB, SMW + ORZ2, 0, acc, u);
      #pragma unroll
      for (int j=0;j<4;j++) Zb[sS*SZ + u + 16*j] = (f16)acc[j];
    }
    wave_sync();
    { // hid = gelu([z,y,gf] @ ry1 + ryb1)
      float acc[4];
      #pragma unroll
      for (int j=0;j<4;j++) acc[j] = ryb1[u + 16*j];
      mvg<4, 8,26>(xZ, SMW + ORY1, 0,  acc, u);
      mvg<4,16,26>(xA, SMW + ORY1, 8,  acc, u);
      mvg<4, 2,26>(xG, SMW + ORY1, 24, acc, u);
      #pragma unroll
      for (int j=0;j<4;j++) Bb[sS*SA + u + 16*j] = (f16)geluf(acc[j]);
    }
    wave_sync();
    { // y = hid @ ry2 + ryb2
      float acc[8];
      #pragma unroll
      for (int j=0;j<8;j++) acc[j] = ryb2[u + 16*j];
      mvg<8,8,8>(xB, SMW + ORY2, 0, acc, u);
      #pragma unroll
      for (int j=0;j<8;j++) A[sS*SA + u + 16*j] = (f16)acc[j];
    }
    wave_sync();
  }

  // selector
  {
    float acc[4];
    #pragma unroll
    for (int j=0;j<4;j++) acc[j] = sb1[u + 16*j];
    mvg<4,16,16>(xA, SMW + OS1, 0, acc, u);
    #pragma unroll
    for (int j=0;j<4;j++) Bb[sS*SA + u + 16*j] = (f16)geluf(acc[j]);
  }
  wave_sync();
  {
    float acc[4];
    #pragma unroll
    for (int j=0;j<4;j++) acc[j] = sb2[u + 16*j];
    mvg<4,8,8>(xB, SMW + OS2, 0, acc, u);
    #pragma unroll
    for (int j=0;j<4;j++) Lb[sS*SLOG + u + 16*j] = acc[j] + gum[gsamp*64 + u + 16*j];
  }
  wave_sync();

  // softmax (each of the 16 threads of a sample redundantly reduces its row)
  {
    const float* row = Lb + sS*SLOG;
    float m = -3.0e38f;
    #pragma unroll
    for (int k4=0;k4<16;k4++){
      float4 v = *(const float4*)(row + k4*4);
      m = fmaxf(m, fmaxf(fmaxf(v.x,v.y), fmaxf(v.z,v.w)));
    }
    float ssum = 0.f;
    #pragma unroll
    for (int k4=0;k4<16;k4++){
      float4 v = *(const float4*)(row + k4*4);
      ssum += __expf(v.x-m)+__expf(v.y-m)+__expf(v.z-m)+__expf(v.w-m);
    }
    float inv = 1.0f / ssum;
    #pragma unroll
    for (int j=0;j<4;j++){
      int o = u + 16*j;
      out[gsamp*64 + o] = __expf(row[o]-m) * inv;
    }
  }
}

extern "C" void kernel_launch(void* const* d_in, const int* in_sizes, int n_in,
                              void* d_out, int out_size, void* d_ws, size_t ws_size,
                              hipStream_t stream) {
  const int*   grd   = (const int*)d_in[0];
  const float* gfeat = (const float*)d_in[1];
  const float* gum   = (const float*)d_in[2];
  const float* w1    = (const float*)d_in[3];
  const float* b1    = (const float*)d_in[4];
  const float* w2    = (const float*)d_in[5];
  const float* b2    = (const float*)d_in[6];
  const float* wy    = (const float*)d_in[7];
  const float* byb   = (const float*)d_in[8];
  const float* wz    = (const float*)d_in[9];
  const float* bz    = (const float*)d_in[10];
  const float* rz1   = (const float*)d_in[11];
  const float* rzb1  = (const float*)d_in[12];
  const float* rz2   = (const float*)d_in[13];
  const float* rzb2  = (const float*)d_in[14];
  const float* ry1   = (const float*)d_in[15];
  const float* ryb1  = (const float*)d_in[16];
  const float* ry2   = (const float*)d_in[17];
  const float* ryb2  = (const float*)d_in[18];
  const float* sel1  = (const float*)d_in[19];
  const float* sb1   = (const float*)d_in[20];
  const float* sel2  = (const float*)d_in[21];
  const float* sb2   = (const float*)d_in[22];

  f16* ws = (f16*)d_ws;
  float* outp = (float*)d_out;

  const int prep_total = N_W1H + N_SMH;
  prep_kernel<<<(prep_total + WG_SIZE - 1)/WG_SIZE, WG_SIZE, 0, stream>>>(
      w1, w2, wy, wz, rz1, rz2, ry1, ry2, sel1, sel2, ws);

  fused_kernel<<<8192/BM, WG_SIZE, 0, stream>>>(
      grd, gfeat, gum, b1, b2, byb, bz, rzb1, rzb2, ryb1, ryb2, sb1, sb2, ws, outp);
}

// Round 3
// 99.161 us; speedup vs baseline: 3.9322x; 1.6473x over previous
//
#include <hip/hip_runtime.h>

typedef _Float16 f16;
typedef f16 h2 __attribute__((ext_vector_type(2)));
typedef f16 h8 __attribute__((ext_vector_type(8)));
typedef float f32x4 __attribute__((ext_vector_type(4)));
typedef unsigned int uint;

#define WG_SIZE 256
#define BM 16
#define NCH 113          // ceil(900/8), 8 positions per chunk

// LDS strides (halves / floats)
#define SH 136           // h / h2 buffers
#define SAZ 232          // [y(128) z(64) gf(16) pad(16)] + 8 stagger
#define SLOG 68
#define CSTR 904         // color row stride (bytes)

// ws layout (halves)
#define N_W1H 1152000    // 9000*128 f16
// small weights, MFMA-fragment-packed: frag = (ntile*KS + kstep), 512 halves each
#define OW2   0
#define OWY   16384
#define OWZ   32768
#define ORZ1  40960
#define ORZ2  55296
#define ORY1  59392
#define ORY2  73728
#define OS1   81920
#define OS2   90112
#define N_SMH 94208

__device__ __forceinline__ float geluf(float x){
  return 0.5f * x * (1.0f + erff(x * 0.70710678118654752f));
}

__device__ __forceinline__ void gll16(const void* g, void* l){
  __builtin_amdgcn_global_load_lds((const __attribute__((address_space(1))) void*)g,
                                   (__attribute__((address_space(3))) void*)l, 16, 0, 0);
}

#define MFMA16(a,b,c) __builtin_amdgcn_mfma_f32_16x16x32_f16(a, b, c, 0, 0, 0)

// one 16x16 C tile over K = nks*32, A from LDS (self-consistent k-map: k = (lane>>4)*8+e),
// B from prep-packed global fragments (same k-map) — 1KB coalesced per load.
__device__ __forceinline__ f32x4 mfma_tile(const f16* __restrict__ act, int strideH,
                                           const f16* __restrict__ Wbase,
                                           int nks, f32x4 acc, int lane){
  #pragma unroll
  for (int ks = 0; ks < nks; ++ks){
    h8 a = *(const h8*)(act + (lane&15)*strideH + ks*32 + (lane>>4)*8);
    h8 b = *(const h8*)(Wbase + ks*512 + lane*8);
    acc = MFMA16(a, b, acc);
  }
  return acc;
}

__device__ __forceinline__ f32x4 cinit(const float* __restrict__ bias, int Nb, int lane){
  float v = bias[Nb + (lane&15)];
  f32x4 c; c[0]=v; c[1]=v; c[2]=v; c[3]=v;
  return c;
}

// C layout (HW-verified): col = lane&15, row = (lane>>4)*4 + reg
__device__ __forceinline__ void storeC16(f16* __restrict__ dst, int stride, int Nb,
                                         f32x4 c, int lane, bool dogelu){
  int col = Nb + (lane&15);
  int r0  = (lane>>4)*4;
  #pragma unroll
  for (int r = 0; r < 4; ++r){
    float v = c[r];
    if (dogelu) v = geluf(v);
    dst[(r0+r)*stride + col] = (f16)v;
  }
}

union H8u { h8 v; h2 p[4]; };

// gather-accumulate over PC positions; lane owns feature granule `gr` (8 features).
template<int PC>
__device__ __forceinline__ void chunkAcc(const f16* __restrict__ wb, uint2 cc,
                                         uint laneoff, float* accF){
  h2 a0, a1, a2, a3;
  a0[0]=(f16)0; a0[1]=(f16)0; a1=a0; a2=a0; a3=a0;
  #pragma unroll
  for (int p = 0; p < PC; ++p){
    uint g = ((p < 4) ? (cc.x >> (8*p)) : (cc.y >> (8*(p-4)))) & 255u;
    // row = p*10+g; addr = row*128 + laneoff; p*10*128 folds into ds_read imm offset
    H8u w; w.v = *(const h8*)(wb + (g<<7) + laneoff + (uint)(p*1280));
    a0 += w.p[0]; a1 += w.p[1]; a2 += w.p[2]; a3 += w.p[3];
  }
  accF[0]+=(float)a0[0]; accF[1]+=(float)a0[1];
  accF[2]+=(float)a1[0]; accF[3]+=(float)a1[1];
  accF[4]+=(float)a2[0]; accF[5]+=(float)a2[1];
  accF[6]+=(float)a3[0]; accF[7]+=(float)a3[1];
}

// ---------------- prep: w1 -> f16 copy; small weights -> MFMA fragment order ----------------
__global__ void prep_kernel(const float* __restrict__ w1,
  const float* __restrict__ w2, const float* __restrict__ wy, const float* __restrict__ wz,
  const float* __restrict__ rz1, const float* __restrict__ rz2,
  const float* __restrict__ ry1, const float* __restrict__ ry2,
  const float* __restrict__ sel1, const float* __restrict__ sel2, f16* __restrict__ ws)
{
  int idx = blockIdx.x * WG_SIZE + threadIdx.x;
  if (idx < N_W1H){ ws[idx] = (f16)w1[idx]; return; }
  int r = idx - N_W1H;
  if (r >= N_SMH) return;
  const float* src; int Ksrc, N, KS, off, perm = 0;
  if      (r < OWY) { src=w2;   Ksrc=128; N=128; KS=4; off=OW2; }
  else if (r < OWZ) { src=wy;   Ksrc=128; N=128; KS=4; off=OWY; }
  else if (r < ORZ1){ src=wz;   Ksrc=128; N=64;  KS=4; off=OWZ; }
  else if (r < ORZ2){ src=rz1;  Ksrc=208; N=64;  KS=7; off=ORZ1; }
  else if (r < ORY1){ src=rz2;  Ksrc=64;  N=64;  KS=2; off=ORZ2; }
  else if (r < ORY2){ src=ry1;  Ksrc=208; N=64;  KS=7; off=ORY1; perm=1; }
  else if (r < OS1) { src=ry2;  Ksrc=64;  N=128; KS=2; off=ORY2; }
  else if (r < OS2) { src=sel1; Ksrc=128; N=64;  KS=4; off=OS1; }
  else              { src=sel2; Ksrc=64;  N=64;  KS=2; off=OS2; }
  int l    = r - off;
  int e    = l & 7;
  int lane = (l >> 3) & 63;
  int frag = l >> 9;
  int kst  = frag % KS;
  int nt   = frag / KS;
  int k    = kst*32 + (lane>>4)*8 + e;
  int o    = nt*16 + (lane&15);
  float v = 0.f;
  if (perm){
    // A k-order is [y(0-127) z(128-191) gf(192-207)]; ry1 src rows are [z(0-63) y(64-191) gf(192-207)]
    int sr = (k < 128) ? 64 + k : (k < 192) ? k - 128 : (k < 208) ? k : -1;
    if (sr >= 0) v = src[sr*N + o];
  } else if (k < Ksrc) v = src[k*N + o];
  ws[N_W1H + r] = (f16)v;
}

// ---------------- fused main kernel ----------------
extern "C" __global__ __launch_bounds__(WG_SIZE, 2) void fused_kernel(
  const int* __restrict__ grd, const float* __restrict__ gfeat, const float* __restrict__ gum,
  const float* __restrict__ b1, const float* __restrict__ b2,
  const float* __restrict__ by, const float* __restrict__ bz,
  const float* __restrict__ rzb1, const float* __restrict__ rzb2,
  const float* __restrict__ ryb1, const float* __restrict__ ryb2,
  const float* __restrict__ sb1, const float* __restrict__ sb2,
  const f16* __restrict__ ws, float* __restrict__ out)
{
  __shared__ __align__(16) char Wbuf[2][20480];
  __shared__ __align__(16) char colL[16*CSTR];
  __shared__ __align__(16) f16 Hb[16*SH];
  __shared__ __align__(16) f16 Bb[16*SH];
  __shared__ __align__(16) f16 Az[16*SAZ];
  __shared__ __align__(16) float Lb[16*SLOG];

  const int t  = threadIdx.x;
  const int s0 = blockIdx.x * BM;
  const int flane = t & 15;
  const int slane = t >> 4;
  // bank-conflict relabel: lane owns feature granule (flane + 4*(lane>>4))&15  (8->4-way)
  const int gr   = (flane + ((slane & 3) << 2)) & 15;
  const int foff = gr * 8;

  // ---- prologue: pack colors (u8), stage grid features into Az, zero K-pad ----
  {
    const uint4* gv = (const uint4*)(grd + (size_t)s0 * 900);
    #pragma unroll
    for (int it = 0; it < 15; ++it){
      int idx4 = it*256 + t;
      if (idx4 < 3600){
        uint4 v = gv[idx4];
        uint pk = (v.x & 255u) | ((v.y & 255u) << 8) | ((v.z & 255u) << 16) | ((v.w & 255u) << 24);
        uint s  = (uint)(idx4 * 9321u) >> 21;   // idx4 / 225
        uint p4 = (uint)idx4 - s * 225u;
        *(uint*)(colL + s*CSTR + p4*4) = pk;
      }
    }
    Az[slane*SAZ + 192 + flane] = (f16)gfeat[(size_t)(s0 + slane)*16 + flane];
    Az[slane*SAZ + 208 + flane] = (f16)0.f;
  }
  __syncthreads();   // drains prior vmem -> vmcnt baseline 0

  // ---- phase E: h = gelu(onehot(grid) @ w1 + b1), LDS-gather form ----
  float accF[8] = {0,0,0,0,0,0,0,0};

  auto issueChunk = [&](int c, char* dst){
    const char* src = (const char*)(ws + (size_t)c * 10240);
    #pragma unroll
    for (int i = 0; i < 5; ++i)
      gll16(src + i*4096 + t*16, dst + i*4096 + t*16);
  };

  issueChunk(0, Wbuf[0]);
  issueChunk(1, Wbuf[1]);
  asm volatile("s_waitcnt vmcnt(5)" ::: "memory");
  __builtin_amdgcn_s_barrier();

  uint2 cc = *(const uint2*)(colL + slane*CSTR);
  #pragma unroll 1
  for (int c = 0; c < NCH; ++c){
    f16* wb = (f16*)Wbuf[c & 1];
    uint2 ccn = cc;
    if (c + 1 < NCH) ccn = *(const uint2*)(colL + slane*CSTR + (c+1)*8);
    if (c != NCH-1) chunkAcc<8>(wb, cc, (uint)foff, accF);
    else            chunkAcc<4>(wb, cc, (uint)foff, accF);
    cc = ccn;
    __builtin_amdgcn_s_barrier();
    if (c + 2 < NCH){
      issueChunk(c + 2, (char*)wb);
      asm volatile("s_waitcnt vmcnt(5)" ::: "memory");
    } else if (c + 2 == NCH){
      asm volatile("s_waitcnt vmcnt(0)" ::: "memory");
    }
    __builtin_amdgcn_s_barrier();
  }

  { // bias + gelu -> h (f16)
    float4 bl = *(const float4*)(b1 + foff);
    float4 bh = *(const float4*)(b1 + foff + 4);
    h8 hv;
    hv[0] = (f16)geluf(accF[0] + bl.x);
    hv[1] = (f16)geluf(accF[1] + bl.y);
    hv[2] = (f16)geluf(accF[2] + bl.z);
    hv[3] = (f16)geluf(accF[3] + bl.w);
    hv[4] = (f16)geluf(accF[4] + bh.x);
    hv[5] = (f16)geluf(accF[5] + bh.y);
    hv[6] = (f16)geluf(accF[6] + bh.z);
    hv[7] = (f16)geluf(accF[7] + bh.w);
    *(h8*)(Hb + slane*SH + foff) = hv;
  }
  __syncthreads();

  // ---- phases 2-4: MFMA, 16 samples per wave, 4 waves split output slices ----
  const f16* SMW = ws + N_W1H;
  const int lane = t & 63;
  const int w    = t >> 6;

  // enc L2: h2 = gelu(h @ w2 + b2)   K=128, N=128
  {
    f32x4 c0 = cinit(b2, w*32,      lane);
    f32x4 c1 = cinit(b2, w*32 + 16, lane);
    c0 = mfma_tile(Hb, SH, SMW + OW2 + (w*2+0)*4*512, 4, c0, lane);
    c1 = mfma_tile(Hb, SH, SMW + OW2 + (w*2+1)*4*512, 4, c1, lane);
    storeC16(Bb, SH, w*32,      c0, lane, true);
    storeC16(Bb, SH, w*32 + 16, c1, lane, true);
  }
  __syncthreads();

  // heads: y = h2@wy+by (N=128) ; z = h2@wz+bz (N=64)
  {
    f32x4 y0 = cinit(by, w*32,      lane);
    f32x4 y1 = cinit(by, w*32 + 16, lane);
    f32x4 z0 = cinit(bz, w*16,      lane);
    y0 = mfma_tile(Bb, SH, SMW + OWY + (w*2+0)*4*512, 4, y0, lane);
    y1 = mfma_tile(Bb, SH, SMW + OWY + (w*2+1)*4*512, 4, y1, lane);
    z0 = mfma_tile(Bb, SH, SMW + OWZ + w*4*512,       4, z0, lane);
    storeC16(Az, SAZ, w*32,       y0, lane, false);
    storeC16(Az, SAZ, w*32 + 16,  y1, lane, false);
    storeC16(Az, SAZ, 128 + w*16, z0, lane, false);
  }
  __syncthreads();

  // 3 refinement cycles
  #pragma unroll 1
  for (int cyc = 0; cyc < 3; ++cyc){
    { // hid = gelu([y,z,gf] @ rz1 + rzb1)   K=224, N=64
      f32x4 h0 = cinit(rzb1, w*16, lane);
      h0 = mfma_tile(Az, SAZ, SMW + ORZ1 + w*7*512, 7, h0, lane);
      storeC16(Bb, SH, w*16, h0, lane, true);
    }
    __syncthreads();
    { // z = hid @ rz2 + rzb2   K=64, N=64
      f32x4 z = cinit(rzb2, w*16, lane);
      z = mfma_tile(Bb, SH, SMW + ORZ2 + w*2*512, 2, z, lane);
      storeC16(Az, SAZ, 128 + w*16, z, lane, false);
    }
    __syncthreads();
    { // hid = gelu([z,y,gf] @ ry1 + ryb1)   K=224 (perm-packed), N=64
      f32x4 h1 = cinit(ryb1, w*16, lane);
      h1 = mfma_tile(Az, SAZ, SMW + ORY1 + w*7*512, 7, h1, lane);
      storeC16(Bb, SH, w*16, h1, lane, true);
    }
    __syncthreads();
    { // y = hid @ ry2 + ryb2   K=64, N=128
      f32x4 y0 = cinit(ryb2, w*32,      lane);
      f32x4 y1 = cinit(ryb2, w*32 + 16, lane);
      y0 = mfma_tile(Bb, SH, SMW + ORY2 + (w*2+0)*2*512, 2, y0, lane);
      y1 = mfma_tile(Bb, SH, SMW + ORY2 + (w*2+1)*2*512, 2, y1, lane);
      storeC16(Az, SAZ, w*32,      y0, lane, false);
      storeC16(Az, SAZ, w*32 + 16, y1, lane, false);
    }
    __syncthreads();
  }

  // selector: logits = mlp2(y)
  {
    f32x4 s1 = cinit(sb1, w*16, lane);
    s1 = mfma_tile(Az, SAZ, SMW + OS1 + w*4*512, 4, s1, lane);   // K=128 (y cols of Az)
    storeC16(Bb, SH, w*16, s1, lane, true);
  }
  __syncthreads();
  {
    f32x4 lg = cinit(sb2, w*16, lane);
    lg = mfma_tile(Bb, SH, SMW + OS2 + w*2*512, 2, lg, lane);
    int col = w*16 + (lane & 15);
    int r0  = (lane >> 4) * 4;
    #pragma unroll
    for (int rr = 0; rr < 4; ++rr)
      Lb[(r0+rr)*SLOG + col] = lg[rr] + gum[(size_t)(s0 + r0 + rr)*64 + col];
  }
  __syncthreads();

  // softmax (16 threads/sample, redundant row reduce)
  {
    const float* row = Lb + slane*SLOG;
    float m = -3.0e38f;
    #pragma unroll
    for (int k4 = 0; k4 < 16; ++k4){
      float4 v = *(const float4*)(row + k4*4);
      m = fmaxf(m, fmaxf(fmaxf(v.x,v.y), fmaxf(v.z,v.w)));
    }
    float ssum = 0.f;
    #pragma unroll
    for (int k4 = 0; k4 < 16; ++k4){
      float4 v = *(const float4*)(row + k4*4);
      ssum += __expf(v.x-m)+__expf(v.y-m)+__expf(v.z-m)+__expf(v.w-m);
    }
    float inv = 1.0f / ssum;
    const size_t gsamp = (size_t)(s0 + slane);
    #pragma unroll
    for (int j = 0; j < 4; ++j){
      int o = flane + 16*j;
      out[gsamp*64 + o] = __expf(row[o]-m) * inv;
    }
  }
}

extern "C" void kernel_launch(void* const* d_in, const int* in_sizes, int n_in,
                              void* d_out, int out_size, void* d_ws, size_t ws_size,
                              hipStream_t stream) {
  const int*   grd   = (const int*)d_in[0];
  const float* gfeat = (const float*)d_in[1];
  const float* gum   = (const float*)d_in[2];
  const float* w1    = (const float*)d_in[3];
  const float* b1    = (const float*)d_in[4];
  const float* w2    = (const float*)d_in[5];
  const float* b2    = (const float*)d_in[6];
  const float* wy    = (const float*)d_in[7];
  const float* byb   = (const float*)d_in[8];
  const float* wz    = (const float*)d_in[9];
  const float* bz    = (const float*)d_in[10];
  const float* rz1   = (const float*)d_in[11];
  const float* rzb1  = (const float*)d_in[12];
  const float* rz2   = (const float*)d_in[13];
  const float* rzb2  = (const float*)d_in[14];
  const float* ry1   = (const float*)d_in[15];
  const float* ryb1  = (const float*)d_in[16];
  const float* ry2   = (const float*)d_in[17];
  const float* ryb2  = (const float*)d_in[18];
  const float* sel1  = (const float*)d_in[19];
  const float* sb1   = (const float*)d_in[20];
  const float* sel2  = (const float*)d_in[21];
  const float* sb2   = (const float*)d_in[22];

  f16* ws = (f16*)d_ws;
  float* outp = (float*)d_out;

  const int prep_total = N_W1H + N_SMH;
  prep_kernel<<<(prep_total + WG_SIZE - 1)/WG_SIZE, WG_SIZE, 0, stream>>>(
      w1, w2, wy, wz, rz1, rz2, ry1, ry2, sel1, sel2, ws);

  fused_kernel<<<8192/BM, WG_SIZE, 0, stream>>>(
      grd, gfeat, gum, b1, b2, byb, bz, rzb1, rzb2, ryb1, ryb2, sb1, sb2, ws, outp);
}